// Round 8
// baseline (178.698 us; speedup 1.0000x reference)
//
#include <hip/hip_runtime.h>

// Fused Bahdanau context-attention pooling, MI355X (gfx950).
// R8 = R7 with the staging index bug fixed (full 2048-float4 coverage:
// 32 loads/lane in 4 batches of 8). Structure: R3's barrier-free
// one-wave-per-block (best measured per-wave memory efficiency) with a
// 16-row tile so LDS = 16.6 KB -> ~9 blocks/CU.
//   K1 prep     : q = query@Wq^T (f32), Wk -> bf16 in ws, mask-layout flag
//   K2 main     : ONE WAVE per (b, 16-row chunk): 4x8 back-to-back float4
//                 HBM loads/lane -> packed bf16 XOR-swizzled LDS tile; proj
//                 via mfma 16x16x32 (acc[8], full 128 a-cols); in-wave score
//                 tanh(q+k)*Ws + softmax (m,d); ctx partial from LDS.
//   K3 combineA : per b: global M, D over 256 chunk (m,d); scl[j]
//   K4 combineB : context = sum_j scl_j*ctxp_j ; weights = exp(score-M)/D

typedef __attribute__((ext_vector_type(8))) short short8;
typedef __attribute__((ext_vector_type(4))) float f32x4;

#define S_LEN 4096
#define BATCH 32
#define KVD 512
#define AD 128
#define CHN 16                           // rows per block (one wave)
#define GRPS_PER_B (S_LEN / CHN)         // 256
#define NBLK (BATCH * GRPS_PER_B)        // 8192

// ws byte offsets (ws ~1 GB per harness poison-fill size)
#define FLAG_OFF   0
#define Q_OFF      1024
#define WK_OFF     17408        // + 128*512*2  = 131072 -> 148480
#define SCORES_OFF 148480       // + 32*4096*4  = 524288 -> 672768
#define MD_OFF     672768       // + 8192*2*4   = 65536  -> 738304
#define CTXP_OFF   738304       // + 8192*512*4 = 16777216 -> 17515520
#define SCL_OFF    17515520     // + 32*256*4   = 32768  -> 17548288
#define MD2_OFF    17548288     // + 32*2*4

__device__ __forceinline__ unsigned short f2bf_rne(float f) {
  unsigned int u = __float_as_uint(f);
  u = (u + 0x7FFFu + ((u >> 16) & 1u)) >> 16;
  return (unsigned short)u;
}
// round-half-up pack of 2 f32 -> 1 dword of 2 bf16 (lo, hi)
__device__ __forceinline__ unsigned int packbf(float a, float b) {
  unsigned int lo = __float_as_uint(a) + 0x8000u;
  unsigned int hi = __float_as_uint(b) + 0x8000u;
  return (lo >> 16) | (hi & 0xFFFF0000u);
}
__device__ __forceinline__ float tanh_fast(float x) {
  return 1.0f - 2.0f / (1.0f + __expf(2.0f * x));
}

__global__ __launch_bounds__(256) void prep_kernel(
    const float* __restrict__ query, const float* __restrict__ Wq,
    const float* __restrict__ Wk, const void* __restrict__ maskp,
    float* __restrict__ qws, unsigned short* __restrict__ wkb,
    int* __restrict__ flagp) {
  int blk = blockIdx.x, t = threadIdx.x;
  if (blk < 32) {
    __shared__ float qrow[KVD];
    qrow[t] = query[blk * KVD + t];
    qrow[t + 256] = query[blk * KVD + t + 256];
    __syncthreads();
    int a = t >> 1, half = t & 1;
    const float4* wq4 = (const float4*)(Wq + (size_t)a * KVD + half * 256);
    const float4* qr4 = (const float4*)(qrow + half * 256);
    float s = 0.f;
#pragma unroll 8
    for (int i = 0; i < 64; ++i) {
      float4 wv = wq4[i], qv = qr4[i];
      s += wv.x * qv.x + wv.y * qv.y + wv.z * qv.z + wv.w * qv.w;
    }
    s += __shfl_xor(s, 1);
    if (half == 0) qws[blk * AD + a] = s;
  } else if (blk < 40) {
    int j = blk - 32;
    const float4* src = (const float4*)Wk;
#pragma unroll 4
    for (int i = 0; i < 8; ++i) {
      int idx4 = j * 2048 + i * 256 + t;
      float4 v = src[idx4];
      ushort4 o;
      o.x = f2bf_rne(v.x); o.y = f2bf_rne(v.y);
      o.z = f2bf_rne(v.z); o.w = f2bf_rne(v.w);
      ((ushort4*)wkb)[idx4] = o;
    }
  } else {
    __shared__ int okv;
    if (t == 0) okv = 1;
    __syncthreads();
    if (t < 128) {
      int wv = ((const int*)maskp)[t];
      if (!(wv == 0 || wv == 1)) okv = 0;
    }
    __syncthreads();
    if (t == 0) flagp[0] = okv;  // 1 = int32 layout, 0 = byte layout
  }
}

__global__ __launch_bounds__(64) void main_kernel(
    const float* __restrict__ kv, const void* __restrict__ maskp,
    const float* __restrict__ Ws, const float* __restrict__ qws,
    const unsigned short* __restrict__ wkb, const int* __restrict__ flagp,
    float* __restrict__ scores, float* __restrict__ md,
    float* __restrict__ ctxp) {
  int lane = threadIdx.x;
  int g = blockIdx.x;                  // 16-row group id
  int b = g >> 8;
  int s0 = (g & 255) * CHN;            // first row within b
  int lr = lane & 15, lg = lane >> 4;

  __shared__ char tileb[CHN * 1024];   // 16 rows x 512 bf16, XOR-swizzled
  __shared__ float escf[CHN];

  // early small loads (L2-hot), overlap with staging
  int flag = flagp[0];
  int mload = 0;
  if (lane < CHN) {
    int gs = b * S_LEN + s0 + lane;
    mload = flag ? ((const int*)maskp)[gs]
                 : (int)((const unsigned char*)maskp)[gs];
  }
  float qv[8], wv[8];
#pragma unroll
  for (int n = 0; n < 8; ++n) {
    qv[n] = qws[b * AD + n * 16 + lr];
    wv[n] = Ws[n * 16 + lr];
  }

  // ---- stage: 16 rows x 512 f32 (32KB contiguous) -> swizzled bf16 LDS ----
  // 2048 float4 units; 32 loads/lane as 4 batches of 8 back-to-back.
  const float4* src4 = (const float4*)(kv + ((size_t)b * S_LEN + s0) * KVD);
#pragma unroll 1
  for (int i = 0; i < 4; ++i) {
    float4 v[8];
#pragma unroll
    for (int j = 0; j < 8; ++j) v[j] = src4[i * 512 + j * 64 + lane];
#pragma unroll
    for (int j = 0; j < 8; ++j) {
      int f = i * 512 + j * 64 + lane;
      int r = f >> 7, u = f & 127;     // row, float4-col
      uint2 w;
      w.x = packbf(v[j].x, v[j].y);
      w.y = packbf(v[j].z, v[j].w);
      *(uint2*)(tileb + ((r * 1024 + u * 8) ^ ((r & 7) << 4))) = w;
    }
  }
  __syncthreads();  // single wave: fence + lgkm drain

  // ---- projection: C[s(16)][a(128)] = kv @ Wk^T, 16x16x32 bf16 MFMA ----
  f32x4 acc[8];
#pragma unroll
  for (int n = 0; n < 8; ++n) acc[n] = (f32x4)0.f;

  const unsigned short* brow = wkb + (size_t)lr * KVD + lg * 8;
  const char* ta = tileb + lr * 1024;
  int axor = (lr & 7) << 4;

  for (int kk = 0; kk < KVD / 32; ++kk) {
    short8 af = *(const short8*)(ta + ((kk * 64 + lg * 16) ^ axor));
#pragma unroll
    for (int n = 0; n < 8; ++n) {
      short8 bf = *(const short8*)(brow + (size_t)n * 16 * KVD + kk * 32);
      acc[n] = __builtin_amdgcn_mfma_f32_16x16x32_bf16(af, bf, acc[n], 0, 0, 0);
    }
  }

  // ---- scores: D layout col a = 16n+lr, row s = 4lg+reg ----
  float sc[4];
#pragma unroll
  for (int reg = 0; reg < 4; ++reg) {
    float v = 0.f;
#pragma unroll
    for (int n = 0; n < 8; ++n)
      v += tanh_fast(qv[n] + acc[n][reg]) * wv[n];
    v += __shfl_xor(v, 1);
    v += __shfl_xor(v, 2);
    v += __shfl_xor(v, 4);
    v += __shfl_xor(v, 8);
    int row = 4 * lg + reg;
    int mk = __shfl(mload, row);
    sc[reg] = mk ? v : -INFINITY;
  }

  // ---- in-wave softmax over 16 rows ----
  float m = fmaxf(fmaxf(sc[0], sc[1]), fmaxf(sc[2], sc[3]));
  m = fmaxf(m, __shfl_xor(m, 16));
  m = fmaxf(m, __shfl_xor(m, 32));
  float e[4], d = 0.f;
#pragma unroll
  for (int reg = 0; reg < 4; ++reg) {
    e[reg] = (sc[reg] == -INFINITY) ? 0.f : __expf(sc[reg] - m);
    d += e[reg];
  }
  d += __shfl_xor(d, 16);
  d += __shfl_xor(d, 32);

  if (lr == 0) {
#pragma unroll
    for (int reg = 0; reg < 4; ++reg) {
      int row = 4 * lg + reg;
      escf[row] = e[reg];
      scores[b * S_LEN + s0 + row] = sc[reg];
    }
  }
  if (lane == 0) {
    md[g * 2] = (d > 0.f) ? m : -INFINITY;
    md[g * 2 + 1] = d;
  }
  __syncthreads();  // single wave: escf fence

  // ---- partial context from LDS tile: ctx[c] = sum_s e_s * kv[s][c] ----
  float4 c0 = make_float4(0.f, 0.f, 0.f, 0.f);
  float4 c1 = make_float4(0.f, 0.f, 0.f, 0.f);
#pragma unroll 4
  for (int s = 0; s < CHN; ++s) {
    float ev = escf[s];
    uint4 u = *(const uint4*)(tileb + ((s * 1024 + lane * 16) ^ ((s & 7) << 4)));
    c0.x += ev * __uint_as_float(u.x << 16);
    c0.y += ev * __uint_as_float(u.x & 0xFFFF0000u);
    c0.z += ev * __uint_as_float(u.y << 16);
    c0.w += ev * __uint_as_float(u.y & 0xFFFF0000u);
    c1.x += ev * __uint_as_float(u.z << 16);
    c1.y += ev * __uint_as_float(u.z & 0xFFFF0000u);
    c1.z += ev * __uint_as_float(u.w << 16);
    c1.w += ev * __uint_as_float(u.w & 0xFFFF0000u);
  }
  float* cp = ctxp + (size_t)g * KVD + lane * 8;
  *(float4*)cp = c0;
  *(float4*)(cp + 4) = c1;
}

__global__ __launch_bounds__(256) void combineA_kernel(
    const float* __restrict__ md, float* __restrict__ scl,
    float* __restrict__ md2) {
  int b = blockIdx.x, t = threadIdx.x;  // 256 threads = 4 waves, 256 groups
  float mv = md[(b * GRPS_PER_B + t) * 2];
  float dv = md[(b * GRPS_PER_B + t) * 2 + 1];
  __shared__ float rmax[4], rsum[4];
  float m = mv;
  m = fmaxf(m, __shfl_xor(m, 1));
  m = fmaxf(m, __shfl_xor(m, 2));
  m = fmaxf(m, __shfl_xor(m, 4));
  m = fmaxf(m, __shfl_xor(m, 8));
  m = fmaxf(m, __shfl_xor(m, 16));
  m = fmaxf(m, __shfl_xor(m, 32));
  if ((t & 63) == 0) rmax[t >> 6] = m;
  __syncthreads();
  float M = fmaxf(fmaxf(rmax[0], rmax[1]), fmaxf(rmax[2], rmax[3]));
  float e = (dv > 0.f) ? __expf(mv - M) : 0.f;
  float pd = e * dv;
  pd += __shfl_xor(pd, 1);
  pd += __shfl_xor(pd, 2);
  pd += __shfl_xor(pd, 4);
  pd += __shfl_xor(pd, 8);
  pd += __shfl_xor(pd, 16);
  pd += __shfl_xor(pd, 32);
  if ((t & 63) == 0) rsum[t >> 6] = pd;
  __syncthreads();
  float D = rsum[0] + rsum[1] + rsum[2] + rsum[3];
  float invD = 1.f / D;
  scl[b * GRPS_PER_B + t] = e * invD;
  if (t == 0) { md2[b * 2] = M; md2[b * 2 + 1] = invD; }
}

__global__ __launch_bounds__(256) void combineB_kernel(
    const float* __restrict__ scl, const float* __restrict__ md2,
    const float* __restrict__ ctxp, const float* __restrict__ scores,
    float* __restrict__ out) {
  int strip = blockIdx.x, b = blockIdx.y, t = threadIdx.x;
  if (strip < 8) {
    __shared__ float part[4][64];
    int c = strip * 64 + (t & 63);
    int jg = t >> 6;
    float sum = 0.f;
    for (int j = jg; j < GRPS_PER_B; j += 4)
      sum += scl[b * GRPS_PER_B + j] *
             ctxp[(size_t)(b * GRPS_PER_B + j) * KVD + c];
    part[jg][t & 63] = sum;
    __syncthreads();
    if (t < 64)
      out[b * KVD + c] = part[0][t] + part[1][t] + part[2][t] + part[3][t];
  } else {
    float M = md2[b * 2], invD = md2[b * 2 + 1];
    int sbase = (strip - 8) * 1024;
#pragma unroll
    for (int i = 0; i < 4; ++i) {
      int s = sbase + i * 256 + t;
      float scv = scores[b * S_LEN + s];
      out[BATCH * KVD + b * S_LEN + s] = __expf(scv - M) * invD;  // -inf -> 0
    }
  }
}

extern "C" void kernel_launch(void* const* d_in, const int* in_sizes, int n_in,
                              void* d_out, int out_size, void* d_ws, size_t ws_size,
                              hipStream_t stream) {
  const float* query = (const float*)d_in[0];
  const float* kv    = (const float*)d_in[1];
  const void*  maskp = d_in[2];
  const float* Wq    = (const float*)d_in[3];
  const float* Wk    = (const float*)d_in[4];
  const float* Ws    = (const float*)d_in[5];
  float* out = (float*)d_out;
  char* w = (char*)d_ws;
  int* flagp = (int*)(w + FLAG_OFF);
  float* qws = (float*)(w + Q_OFF);
  unsigned short* wkb = (unsigned short*)(w + WK_OFF);
  float* scores = (float*)(w + SCORES_OFF);
  float* md = (float*)(w + MD_OFF);
  float* ctxp = (float*)(w + CTXP_OFF);
  float* scl = (float*)(w + SCL_OFF);
  float* md2 = (float*)(w + MD2_OFF);

  prep_kernel<<<41, 256, 0, stream>>>(query, Wq, Wk, maskp, qws, wkb, flagp);
  main_kernel<<<NBLK, 64, 0, stream>>>(kv, maskp, Ws, qws, wkb, flagp,
                                       scores, md, ctxp);
  combineA_kernel<<<BATCH, 256, 0, stream>>>(md, scl, md2);
  combineB_kernel<<<dim3(12, BATCH), 256, 0, stream>>>(scl, md2, ctxp, scores, out);
}